// Round 3
// baseline (7647.861 us; speedup 1.0000x reference)
//
#include <hip/hip_runtime.h>
#include <math.h>

// ODE-RNN forward: B=1024, T=100, D=32, H=256, MID=50 (padded 64), RK4x4.
// Round 3: fix R2's spill catastrophe (439MB scratch writes, 10.3GB fetch).
// Persistent ODE weights cut to 64 VGPRs (no-duplication tiles: L1 4n x 8k,
// L2 4c x 8k), launch_bounds(512,1) -> 256-VGPR cap. Everything else keeps
// R2 structure: 512 thr, 4 rows/block, stride-20 partial slots (0-conflict).

#define NT 512

// ---------------- ws layout (floats), all packed-k float4 ----------------
#define WS_WCAT 0        // [72 g][256 j][4 c]  k=4g+c over concat [x(32); h(256)]
#define WS_L1P  73728    // [64 g][128 j][4 c]
#define WS_SW1  106496   // [64 g][256 j][4 c]
#define WS_TOT  172032

// ---------------- LDS layout (floats) ----------------
#define SM_PR1 0        // 512*20 partial slots
#define SM_PR2 10240    // 512*20
#define SM_H   20480    // [4][256] flat
#define SM_YC  21504    // [4][256] (alias l1o[4][128])
#define SM_AC  22528    // [4][256] (alias sg[4][256])
#define SM_MD  23552    // [4][64]
#define SM_X4  23808    // [4][32]
#define SM_BC  23936    // 256
#define SM_OB1 24192    // 64
#define SM_OB2 24256    // 256
#define SM_L1B 24512    // 128
#define SM_SB1 24640    // 256
#define SM_MUW 24896    // 128
#define SM_SW2 25024    // 256
#define SM_SCL 25280    // 8
#define SM_TOT 25288
#define SMEM_BYTES (SM_TOT * 4)

__device__ __forceinline__ float fma4(float acc, float4 y, float4 w) {
  acc = fmaf(y.x, w.x, acc);
  acc = fmaf(y.y, w.y, acc);
  acc = fmaf(y.z, w.z, acc);
  acc = fmaf(y.w, w.w, acc);
  return acc;
}

__device__ __forceinline__ float tfast(float x) {
  float ax = fabsf(x);
  float e  = __expf(-2.f * ax);
  float t  = (1.f - e) * __builtin_amdgcn_rcpf(1.f + e);
  return copysignf(t, x);
}

__global__ void prep_transpose(const float* __restrict__ Wih,
                               const float* __restrict__ Whh,
                               const float* __restrict__ l1w,
                               const float* __restrict__ sw1,
                               float* __restrict__ ws) {
  int i = blockIdx.x * 256 + threadIdx.x;
  if (i < 73728) {                       // Wcat4
    int g = i >> 10, rem = i & 1023, j = rem >> 2, c = rem & 3;
    int k = 4 * g + c;
    ws[i] = (k < 32) ? Wih[j * 32 + k] : Whh[j * 256 + (k - 32)];
  } else if (i < 106496) {               // l1p4
    int t = i - 73728;
    int g = t >> 9, rem = t & 511, j = rem >> 2, c = rem & 3;
    ws[i] = l1w[j * 256 + 4 * g + c];
  } else if (i < WS_TOT) {               // sw1p4
    int t = i - 106496;
    int g = t >> 10, rem = t & 1023, j = rem >> 2, c = rem & 3;
    ws[i] = sw1[j * 256 + 4 * g + c];
  }
}

__launch_bounds__(NT, 1)
__global__ void odernn_main(const float* __restrict__ dt,
                            const float* __restrict__ x,
                            const float* __restrict__ bih,
                            const float* __restrict__ bhh,
                            const float* __restrict__ ow1,
                            const float* __restrict__ ob1g,
                            const float* __restrict__ ow2,
                            const float* __restrict__ ob2g,
                            const float* __restrict__ l1bg,
                            const float* __restrict__ muwg,
                            const float* __restrict__ mubg,
                            const float* __restrict__ sb1g,
                            const float* __restrict__ sw2g,
                            const float* __restrict__ sb2g,
                            const float* __restrict__ ws,
                            float* __restrict__ out) {
  extern __shared__ __align__(16) float sm[];
  const int tid = threadIdx.x;
  const int wv = tid >> 6, ln = tid & 63;
  const int b0 = blockIdx.x * 4;

  float* prS  = sm + SM_PR1;
  float* prS2 = sm + SM_PR2;
  float* hS   = sm + SM_H;
  float* ycS  = sm + SM_YC;
  float* acS  = sm + SM_AC;
  float* mdS  = sm + SM_MD;
  float* x4S  = sm + SM_X4;
  float* bcS  = sm + SM_BC;
  float* ob1S = sm + SM_OB1;
  float* ob2S = sm + SM_OB2;
  float* l1bS = sm + SM_L1B;
  float* sb1S = sm + SM_SB1;
  float* muwS = sm + SM_MUW;
  float* sw2S = sm + SM_SW2;
  float* sclS = sm + SM_SCL;
  float* l1oS = ycS;
  float* sgS  = acS;

  float4* pr1_4 = (float4*)prS;
  float4* pr2_4 = (float4*)prS2;
  const float4* h44 = (const float4*)hS;   // [4][64]
  const float4* yc44 = (const float4*)ycS; // [4][64]
  const float4* md4 = (const float4*)mdS;  // [4][16]
  const float4* x44 = (const float4*)x4S;  // [4][8]

  const float4* wcat4 = (const float4*)(ws + WS_WCAT); // f4 idx g*256 + j
  const float4* l1w4  = (const float4*)(ws + WS_L1P);  // f4 idx g*128 + j
  const float4* sw14  = (const float4*)(ws + WS_SW1);  // f4 idx g*256 + j

  // ---- persistent ODE weight registers (64 VGPRs total, no duplication)
  // L1: thread (q1 = tid&15, kc1 = tid>>4): neurons 4q1..4q1+3, k in [8kc1, 8kc1+8)
  // L2: thread (cq2 = tid&63, kc2 = tid>>6): cols 4cq2..4cq2+3, k in [8kc2, 8kc2+8)
  const int q1 = tid & 15, kc1 = tid >> 4;          // kc1 in [0,32)
  const int cq2 = tid & 63, kc2 = tid >> 6;         // kc2 in [0,8)
  float4 w1r[4][2];
  float4 w2r[4][2];
  {
#pragma unroll
    for (int n = 0; n < 4; ++n) {
      int row = 4 * q1 + n;
#pragma unroll
      for (int g = 0; g < 2; ++g) {
        if (row < 50)
          w1r[n][g] = *(const float4*)&ow1[row * 256 + kc1 * 8 + 4 * g];
        else
          w1r[n][g] = make_float4(0.f, 0.f, 0.f, 0.f);
      }
    }
    float w2tmp[4];
#pragma unroll
    for (int n = 0; n < 4; ++n) {
      int col = 4 * cq2 + n;
#pragma unroll
      for (int g = 0; g < 2; ++g) {
#pragma unroll
        for (int c = 0; c < 4; ++c) {
          int k = kc2 * 8 + 4 * g + c;
          w2tmp[c] = (k < 50) ? ow2[col * 50 + k] : 0.f;
        }
        w2r[n][g] = make_float4(w2tmp[0], w2tmp[1], w2tmp[2], w2tmp[3]);
      }
    }
  }

  // ---- one-time staging
  if (tid < 256) {
    bcS[tid]  = bih[tid] + bhh[tid];
    ob2S[tid] = ob2g[tid];
    sb1S[tid] = sb1g[tid];
    sw2S[tid] = sw2g[tid];
  }
  if (tid < 64)  ob1S[tid] = (tid < 50) ? ob1g[tid] : 0.f;
  if (tid < 128) { l1bS[tid] = l1bg[tid]; muwS[tid] = muwg[tid]; }
  hS[tid] = 0.f; hS[tid + 512] = 0.f;
  __syncthreads();

  const float mub = mubg[0], sb2 = sb2g[0];

  for (int t = 0; t < 100; ++t) {
    // ---- stage x tile and per-row scale
    if (tid < 128) {
      int r = tid >> 5, kk = tid & 31;
      x4S[r * 32 + kk] = x[((size_t)(b0 + r) * 100 + t) * 32 + kk];
    }
    if (tid < 4) {
      const float* dp = dt + ((size_t)(b0 + tid) * 100 + t) * 2;
      sclS[tid] = (dp[1] - dp[0]) * (1.f / 24.f);
    }
    __syncthreads();

    // ===== RNN partials: K=288 concat, (jq 64, kc 8), 4 cols x 4 rows
    {
      const int jq = tid & 63, kc = tid >> 6;
      float4 acc0 = make_float4(0, 0, 0, 0), acc1 = acc0, acc2 = acc0, acc3 = acc0;
#pragma unroll
      for (int gg = 0; gg < 9; ++gg) {
        int g = kc * 9 + gg;                         // k = 4g
        float4 w0 = wcat4[g * 256 + 4 * jq + 0];
        float4 w1 = wcat4[g * 256 + 4 * jq + 1];
        float4 w2 = wcat4[g * 256 + 4 * jq + 2];
        float4 w3 = wcat4[g * 256 + 4 * jq + 3];
        float4 y0 = (g < 8) ? x44[0 * 8 + g] : h44[0 * 64 + (g - 8)];
        float4 y1 = (g < 8) ? x44[1 * 8 + g] : h44[1 * 64 + (g - 8)];
        float4 y2 = (g < 8) ? x44[2 * 8 + g] : h44[2 * 64 + (g - 8)];
        float4 y3 = (g < 8) ? x44[3 * 8 + g] : h44[3 * 64 + (g - 8)];
        acc0.x = fma4(acc0.x, y0, w0); acc0.y = fma4(acc0.y, y0, w1);
        acc0.z = fma4(acc0.z, y0, w2); acc0.w = fma4(acc0.w, y0, w3);
        acc1.x = fma4(acc1.x, y1, w0); acc1.y = fma4(acc1.y, y1, w1);
        acc1.z = fma4(acc1.z, y1, w2); acc1.w = fma4(acc1.w, y1, w3);
        acc2.x = fma4(acc2.x, y2, w0); acc2.y = fma4(acc2.y, y2, w1);
        acc2.z = fma4(acc2.z, y2, w2); acc2.w = fma4(acc2.w, y2, w3);
        acc3.x = fma4(acc3.x, y3, w0); acc3.y = fma4(acc3.y, y3, w1);
        acc3.z = fma4(acc3.z, y3, w2); acc3.w = fma4(acc3.w, y3, w3);
      }
      pr1_4[tid * 5 + 0] = acc0;
      pr1_4[tid * 5 + 1] = acc1;
      pr1_4[tid * 5 + 2] = acc2;
      pr1_4[tid * 5 + 3] = acc3;
    }
    __syncthreads();
    // ===== RNN reduce: h += tanh(sum partials + bias)
    {
#pragma unroll
      for (int oo = 0; oo < 2; ++oo) {
        int o = tid + oo * 512;
        int r = o >> 8, j = o & 255;
        int q = j >> 2, n = j & 3;
        float s = bcS[j];
#pragma unroll
        for (int kc = 0; kc < 8; ++kc)
          s += prS[(kc * 64 + q) * 20 + r * 4 + n];
        hS[o] += tfast(s);
      }
    }
    __syncthreads();

    // ===== ODE: 4 RK4 steps, hs = 0.25
#pragma unroll 1
    for (int os = 0; os < 4; ++os) {
#pragma unroll
      for (int s = 0; s < 4; ++s) {
        // --- L1 partials: 4 neurons x 4 rows x 8 k; acc[n] = rows f4
        {
          const float4* ysrc = (s == 0) ? h44 : yc44;
          float4 a0 = make_float4(0, 0, 0, 0), a1 = a0, a2 = a0, a3 = a0;
#pragma unroll
          for (int g = 0; g < 2; ++g) {
            float4 y0 = ysrc[0 * 64 + kc1 * 2 + g];
            float4 y1 = ysrc[1 * 64 + kc1 * 2 + g];
            float4 y2 = ysrc[2 * 64 + kc1 * 2 + g];
            float4 y3 = ysrc[3 * 64 + kc1 * 2 + g];
            a0.x = fma4(a0.x, y0, w1r[0][g]); a0.y = fma4(a0.y, y1, w1r[0][g]);
            a0.z = fma4(a0.z, y2, w1r[0][g]); a0.w = fma4(a0.w, y3, w1r[0][g]);
            a1.x = fma4(a1.x, y0, w1r[1][g]); a1.y = fma4(a1.y, y1, w1r[1][g]);
            a1.z = fma4(a1.z, y2, w1r[1][g]); a1.w = fma4(a1.w, y3, w1r[1][g]);
            a2.x = fma4(a2.x, y0, w1r[2][g]); a2.y = fma4(a2.y, y1, w1r[2][g]);
            a2.z = fma4(a2.z, y2, w1r[2][g]); a2.w = fma4(a2.w, y3, w1r[2][g]);
            a3.x = fma4(a3.x, y0, w1r[3][g]); a3.y = fma4(a3.y, y1, w1r[3][g]);
            a3.z = fma4(a3.z, y2, w1r[3][g]); a3.w = fma4(a3.w, y3, w1r[3][g]);
          }
          pr1_4[tid * 5 + 0] = a0;   // slot tid = kc1*16 + q1
          pr1_4[tid * 5 + 1] = a1;
          pr1_4[tid * 5 + 2] = a2;
          pr1_4[tid * 5 + 3] = a3;
        }
        __syncthreads();
        // --- L1 reduce + tanh -> mdS[r][64]
        if (tid < 256) {
          int j = tid & 63, r = tid >> 6;
          int q = j >> 2, n = j & 3;
          float sv = ob1S[j];
#pragma unroll
          for (int kc = 0; kc < 32; ++kc)
            sv += prS[(kc * 16 + q) * 20 + n * 4 + r];
          mdS[r * 64 + j] = tfast(sv);
        }
        __syncthreads();
        // --- L2 partials: 4 cols x 4 rows x 8 k
        {
          float4 b0v = make_float4(0, 0, 0, 0), b1v = b0v, b2v = b0v, b3v = b0v;
#pragma unroll
          for (int g = 0; g < 2; ++g) {
            float4 m0 = md4[0 * 16 + kc2 * 2 + g];
            float4 m1 = md4[1 * 16 + kc2 * 2 + g];
            float4 m2 = md4[2 * 16 + kc2 * 2 + g];
            float4 m3 = md4[3 * 16 + kc2 * 2 + g];
            b0v.x = fma4(b0v.x, m0, w2r[0][g]); b0v.y = fma4(b0v.y, m1, w2r[0][g]);
            b0v.z = fma4(b0v.z, m2, w2r[0][g]); b0v.w = fma4(b0v.w, m3, w2r[0][g]);
            b1v.x = fma4(b1v.x, m0, w2r[1][g]); b1v.y = fma4(b1v.y, m1, w2r[1][g]);
            b1v.z = fma4(b1v.z, m2, w2r[1][g]); b1v.w = fma4(b1v.w, m3, w2r[1][g]);
            b2v.x = fma4(b2v.x, m0, w2r[2][g]); b2v.y = fma4(b2v.y, m1, w2r[2][g]);
            b2v.z = fma4(b2v.z, m2, w2r[2][g]); b2v.w = fma4(b2v.w, m3, w2r[2][g]);
            b3v.x = fma4(b3v.x, m0, w2r[3][g]); b3v.y = fma4(b3v.y, m1, w2r[3][g]);
            b3v.z = fma4(b3v.z, m2, w2r[3][g]); b3v.w = fma4(b3v.w, m3, w2r[3][g]);
          }
          pr2_4[tid * 5 + 0] = b0v;  // slot tid = kc2*64 + cq2
          pr2_4[tid * 5 + 1] = b1v;
          pr2_4[tid * 5 + 2] = b2v;
          pr2_4[tid * 5 + 3] = b3v;
        }
        __syncthreads();
        // --- L2 reduce + RK4 state update (2 outputs/thread)
        {
#pragma unroll
          for (int oo = 0; oo < 2; ++oo) {
            int o = tid + oo * 512;
            int r = o >> 8, j = o & 255;
            int q = j >> 2, n = j & 3;
            float sv = ob2S[j];
#pragma unroll
            for (int kc = 0; kc < 8; ++kc)
              sv += prS2[(kc * 64 + q) * 20 + n * 4 + r];
            float kv = sv * sclS[r];
            if (s == 0)      { acS[o] = kv;        ycS[o] = hS[o] + 0.125f * kv; }
            else if (s == 1) { acS[o] += 2.f * kv; ycS[o] = hS[o] + 0.125f * kv; }
            else if (s == 2) { acS[o] += 2.f * kv; ycS[o] = hS[o] + 0.25f  * kv; }
            else             { hS[o] += (0.25f / 6.f) * (acS[o] + kv); }
          }
        }
        __syncthreads();
      }
    }

    // ===== heads
    // l1 partials: (cq 32, kc 16): 4 cols x 4 rows x 16 k  -> prS
    {
      const int cq = tid & 31, kc = tid >> 5;
      float4 c0 = make_float4(0, 0, 0, 0), c1 = c0, c2 = c0, c3 = c0;
#pragma unroll
      for (int g = 0; g < 4; ++g) {
        int kg = kc * 4 + g;
        float4 w0 = l1w4[kg * 128 + 4 * cq + 0];
        float4 w1 = l1w4[kg * 128 + 4 * cq + 1];
        float4 w2 = l1w4[kg * 128 + 4 * cq + 2];
        float4 w3 = l1w4[kg * 128 + 4 * cq + 3];
        float4 y0 = h44[0 * 64 + kg], y1 = h44[1 * 64 + kg];
        float4 y2 = h44[2 * 64 + kg], y3 = h44[3 * 64 + kg];
        c0.x = fma4(c0.x, y0, w0); c0.y = fma4(c0.y, y0, w1);
        c0.z = fma4(c0.z, y0, w2); c0.w = fma4(c0.w, y0, w3);
        c1.x = fma4(c1.x, y1, w0); c1.y = fma4(c1.y, y1, w1);
        c1.z = fma4(c1.z, y1, w2); c1.w = fma4(c1.w, y1, w3);
        c2.x = fma4(c2.x, y2, w0); c2.y = fma4(c2.y, y2, w1);
        c2.z = fma4(c2.z, y2, w2); c2.w = fma4(c2.w, y2, w3);
        c3.x = fma4(c3.x, y3, w0); c3.y = fma4(c3.y, y3, w1);
        c3.z = fma4(c3.z, y3, w2); c3.w = fma4(c3.w, y3, w3);
      }
      pr1_4[tid * 5 + 0] = c0;
      pr1_4[tid * 5 + 1] = c1;
      pr1_4[tid * 5 + 2] = c2;
      pr1_4[tid * 5 + 3] = c3;
    }
    // sig1 partials: (cq 64, kc 8): 4 cols x 4 rows x 32 k  -> prS2
    {
      const int cq = tid & 63, kc = tid >> 6;
      float4 d0 = make_float4(0, 0, 0, 0), d1 = d0, d2 = d0, d3 = d0;
#pragma unroll
      for (int g = 0; g < 8; ++g) {
        int kg = kc * 8 + g;
        float4 w0 = sw14[kg * 256 + 4 * cq + 0];
        float4 w1 = sw14[kg * 256 + 4 * cq + 1];
        float4 w2 = sw14[kg * 256 + 4 * cq + 2];
        float4 w3 = sw14[kg * 256 + 4 * cq + 3];
        float4 y0 = h44[0 * 64 + kg], y1 = h44[1 * 64 + kg];
        float4 y2 = h44[2 * 64 + kg], y3 = h44[3 * 64 + kg];
        d0.x = fma4(d0.x, y0, w0); d0.y = fma4(d0.y, y0, w1);
        d0.z = fma4(d0.z, y0, w2); d0.w = fma4(d0.w, y0, w3);
        d1.x = fma4(d1.x, y1, w0); d1.y = fma4(d1.y, y1, w1);
        d1.z = fma4(d1.z, y1, w2); d1.w = fma4(d1.w, y1, w3);
        d2.x = fma4(d2.x, y2, w0); d2.y = fma4(d2.y, y2, w1);
        d2.z = fma4(d2.z, y2, w2); d2.w = fma4(d2.w, y2, w3);
        d3.x = fma4(d3.x, y3, w0); d3.y = fma4(d3.y, y3, w1);
        d3.z = fma4(d3.z, y3, w2); d3.w = fma4(d3.w, y3, w3);
      }
      pr2_4[tid * 5 + 0] = d0;
      pr2_4[tid * 5 + 1] = d1;
      pr2_4[tid * 5 + 2] = d2;
      pr2_4[tid * 5 + 3] = d3;
    }
    __syncthreads();
    // l1 reduce -> relu -> l1oS
    {
      int r = tid >> 7, j2 = tid & 127;
      int q = j2 >> 2, nn = j2 & 3;
      float s = l1bS[j2];
#pragma unroll
      for (int kc = 0; kc < 16; ++kc)
        s += prS[(kc * 32 + q) * 20 + r * 4 + nn];
      l1oS[r * 128 + j2] = fmaxf(s, 0.f);
    }
    // sig1 reduce -> tanh -> sgS
    {
#pragma unroll
      for (int oo = 0; oo < 2; ++oo) {
        int o = tid + oo * 512;
        int r = o >> 8, j = o & 255;
        int q = j >> 2, nn = j & 3;
        float s = sb1S[j];
#pragma unroll
        for (int kc = 0; kc < 8; ++kc)
          s += prS2[(kc * 64 + q) * 20 + r * 4 + nn];
        sgS[o] = tfast(s);
      }
    }
    __syncthreads();
    // final dot-products: wave wv: row = wv&3, head = wv>>2
    {
      const int r = wv & 3;
      if (wv < 4) {
        float pm = l1oS[r * 128 + ln] * muwS[ln]
                 + l1oS[r * 128 + 64 + ln] * muwS[64 + ln];
#pragma unroll
        for (int off = 32; off > 0; off >>= 1) pm += __shfl_down(pm, off);
        if (ln == 0) out[(size_t)(b0 + r) * 100 + t] = pm + mub;
      } else {
        float ps = sgS[r * 256 + ln] * sw2S[ln]
                 + sgS[r * 256 + 64 + ln] * sw2S[64 + ln]
                 + sgS[r * 256 + 128 + ln] * sw2S[128 + ln]
                 + sgS[r * 256 + 192 + ln] * sw2S[192 + ln];
#pragma unroll
        for (int off = 32; off > 0; off >>= 1) ps += __shfl_down(ps, off);
        if (ln == 0) {
          float z = ps + sb2;
          float sp = fmaxf(z, 0.f) + log1pf(expf(-fabsf(z)));
          out[(size_t)102400 + (size_t)(b0 + r) * 100 + t] = sp;
        }
      }
    }
    // no barrier needed: next-step staging writes x4S/sclS (disjoint from
    // l1oS/sgS reads above); first write to prS is after the stage barrier.
  }
}

extern "C" void kernel_launch(void* const* d_in, const int* in_sizes, int n_in,
                              void* d_out, int out_size, void* d_ws, size_t ws_size,
                              hipStream_t stream) {
  const float* dt  = (const float*)d_in[0];
  const float* x   = (const float*)d_in[1];
  const float* Wih = (const float*)d_in[2];
  const float* bih = (const float*)d_in[3];
  const float* Whh = (const float*)d_in[4];
  const float* bhh = (const float*)d_in[5];
  const float* ow1 = (const float*)d_in[6];
  const float* ob1 = (const float*)d_in[7];
  const float* ow2 = (const float*)d_in[8];
  const float* ob2 = (const float*)d_in[9];
  const float* l1w = (const float*)d_in[10];
  const float* l1b = (const float*)d_in[11];
  const float* muw = (const float*)d_in[12];
  const float* mub = (const float*)d_in[13];
  const float* sw1 = (const float*)d_in[14];
  const float* sb1 = (const float*)d_in[15];
  const float* sw2 = (const float*)d_in[16];
  const float* sb2 = (const float*)d_in[17];
  float* ws  = (float*)d_ws;
  float* out = (float*)d_out;

  hipFuncSetAttribute((const void*)odernn_main,
                      hipFuncAttributeMaxDynamicSharedMemorySize, SMEM_BYTES);

  prep_transpose<<<WS_TOT / 256, 256, 0, stream>>>(Wih, Whh, l1w, sw1, ws);
  odernn_main<<<256, NT, SMEM_BYTES, stream>>>(dt, x, bih, bhh, ow1, ob1, ow2, ob2,
                                               l1b, muw, mub, sb1, sw2, sb2, ws, out);
}

// Round 4
// 3591.870 us; speedup vs baseline: 2.1292x; 2.1292x over previous
//
#include <hip/hip_runtime.h>
#include <math.h>

// ODE-RNN forward: B=1024, T=100, D=32, H=256, MID=50 (padded 64), RK4x4.
// Round 4: kill the spill (amdgpu_waves_per_eu(2) -> 256-VGPR cap, bounded
// unroll on global-load loops) and the R3 bank conflicts (ODE partials back
// to col-major f4: f4 lanes = 4 output neurons/cols, slot index = row).
// Structure: 512 thr (8 waves), 4 rows/block, stride-20 partial slots.

#define NT 512

// ---------------- ws layout (floats), all packed-k float4 ----------------
#define WS_WCAT 0        // [72 g][256 j][4 c]  k=4g+c over concat [x(32); h(256)]
#define WS_L1P  73728    // [64 g][128 j][4 c]
#define WS_SW1  106496   // [64 g][256 j][4 c]
#define WS_TOT  172032

// ---------------- LDS layout (floats) ----------------
#define SM_PR1 0        // 512*20 partial slots
#define SM_PR2 10240    // 512*20
#define SM_H   20480    // [4][256] flat
#define SM_YC  21504    // [4][256] (alias l1o[4][128])
#define SM_AC  22528    // [4][256] (alias sg[4][256])
#define SM_MD  23552    // [4][64]
#define SM_X4  23808    // [4][32]
#define SM_BC  23936    // 256
#define SM_OB1 24192    // 64
#define SM_OB2 24256    // 256
#define SM_L1B 24512    // 128
#define SM_SB1 24640    // 256
#define SM_MUW 24896    // 128
#define SM_SW2 25024    // 256
#define SM_SCL 25280    // 8
#define SM_TOT 25288
#define SMEM_BYTES (SM_TOT * 4)

__device__ __forceinline__ float fma4(float acc, float4 y, float4 w) {
  acc = fmaf(y.x, w.x, acc);
  acc = fmaf(y.y, w.y, acc);
  acc = fmaf(y.z, w.z, acc);
  acc = fmaf(y.w, w.w, acc);
  return acc;
}

__device__ __forceinline__ float tfast(float x) {
  float ax = fabsf(x);
  float e  = __expf(-2.f * ax);
  float t  = (1.f - e) * __builtin_amdgcn_rcpf(1.f + e);
  return copysignf(t, x);
}

__global__ void prep_transpose(const float* __restrict__ Wih,
                               const float* __restrict__ Whh,
                               const float* __restrict__ l1w,
                               const float* __restrict__ sw1,
                               float* __restrict__ ws) {
  int i = blockIdx.x * 256 + threadIdx.x;
  if (i < 73728) {                       // Wcat4
    int g = i >> 10, rem = i & 1023, j = rem >> 2, c = rem & 3;
    int k = 4 * g + c;
    ws[i] = (k < 32) ? Wih[j * 32 + k] : Whh[j * 256 + (k - 32)];
  } else if (i < 106496) {               // l1p4
    int t = i - 73728;
    int g = t >> 9, rem = t & 511, j = rem >> 2, c = rem & 3;
    ws[i] = l1w[j * 256 + 4 * g + c];
  } else if (i < WS_TOT) {               // sw1p4
    int t = i - 106496;
    int g = t >> 10, rem = t & 1023, j = rem >> 2, c = rem & 3;
    ws[i] = sw1[j * 256 + 4 * g + c];
  }
}

__global__ __attribute__((amdgpu_flat_work_group_size(NT, NT)))
__attribute__((amdgpu_waves_per_eu(2)))
void odernn_main(const float* __restrict__ dt,
                 const float* __restrict__ x,
                 const float* __restrict__ bih,
                 const float* __restrict__ bhh,
                 const float* __restrict__ ow1,
                 const float* __restrict__ ob1g,
                 const float* __restrict__ ow2,
                 const float* __restrict__ ob2g,
                 const float* __restrict__ l1bg,
                 const float* __restrict__ muwg,
                 const float* __restrict__ mubg,
                 const float* __restrict__ sb1g,
                 const float* __restrict__ sw2g,
                 const float* __restrict__ sb2g,
                 const float* __restrict__ ws,
                 float* __restrict__ out) {
  extern __shared__ __align__(16) float sm[];
  const int tid = threadIdx.x;
  const int wv = tid >> 6, ln = tid & 63;
  const int b0 = blockIdx.x * 4;

  float* prS  = sm + SM_PR1;
  float* prS2 = sm + SM_PR2;
  float* hS   = sm + SM_H;
  float* ycS  = sm + SM_YC;
  float* acS  = sm + SM_AC;
  float* mdS  = sm + SM_MD;
  float* x4S  = sm + SM_X4;
  float* bcS  = sm + SM_BC;
  float* ob1S = sm + SM_OB1;
  float* ob2S = sm + SM_OB2;
  float* l1bS = sm + SM_L1B;
  float* sb1S = sm + SM_SB1;
  float* muwS = sm + SM_MUW;
  float* sw2S = sm + SM_SW2;
  float* sclS = sm + SM_SCL;
  float* l1oS = ycS;
  float* sgS  = acS;

  float4* pr1_4 = (float4*)prS;
  float4* pr2_4 = (float4*)prS2;
  const float4* h44 = (const float4*)hS;   // [4][64]
  const float4* yc44 = (const float4*)ycS; // [4][64]
  const float4* md4 = (const float4*)mdS;  // [4][16]
  const float4* x44 = (const float4*)x4S;  // [4][8]

  const float4* wcat4 = (const float4*)(ws + WS_WCAT); // f4 idx g*256 + j
  const float4* l1w4  = (const float4*)(ws + WS_L1P);  // f4 idx g*128 + j
  const float4* sw14  = (const float4*)(ws + WS_SW1);  // f4 idx g*256 + j

  // ---- persistent ODE weight registers (64 VGPRs total, no duplication)
  // L1: (q1 = tid&15, kc1 = tid>>4): neurons 4q1..+3, k in [8kc1, 8kc1+8)
  // L2: (cq2 = tid&63, kc2 = tid>>6): cols   4cq2..+3, k in [8kc2, 8kc2+8)
  const int q1 = tid & 15, kc1 = tid >> 4;          // kc1 in [0,32)
  const int cq2 = tid & 63, kc2 = tid >> 6;         // kc2 in [0,8)
  float4 w1r[4][2];
  float4 w2r[4][2];
  {
#pragma unroll
    for (int n = 0; n < 4; ++n) {
      int row = 4 * q1 + n;
#pragma unroll
      for (int g = 0; g < 2; ++g) {
        if (row < 50)
          w1r[n][g] = *(const float4*)&ow1[row * 256 + kc1 * 8 + 4 * g];
        else
          w1r[n][g] = make_float4(0.f, 0.f, 0.f, 0.f);
      }
    }
    float w2tmp[4];
#pragma unroll
    for (int n = 0; n < 4; ++n) {
      int col = 4 * cq2 + n;
#pragma unroll
      for (int g = 0; g < 2; ++g) {
#pragma unroll
        for (int c = 0; c < 4; ++c) {
          int k = kc2 * 8 + 4 * g + c;
          w2tmp[c] = (k < 50) ? ow2[col * 50 + k] : 0.f;
        }
        w2r[n][g] = make_float4(w2tmp[0], w2tmp[1], w2tmp[2], w2tmp[3]);
      }
    }
  }

  // ---- one-time staging
  if (tid < 256) {
    bcS[tid]  = bih[tid] + bhh[tid];
    ob2S[tid] = ob2g[tid];
    sb1S[tid] = sb1g[tid];
    sw2S[tid] = sw2g[tid];
  }
  if (tid < 64)  ob1S[tid] = (tid < 50) ? ob1g[tid] : 0.f;
  if (tid < 128) { l1bS[tid] = l1bg[tid]; muwS[tid] = muwg[tid]; }
  hS[tid] = 0.f; hS[tid + 512] = 0.f;
  __syncthreads();

  const float mub = mubg[0], sb2 = sb2g[0];

  for (int t = 0; t < 100; ++t) {
    // ---- stage x tile and per-row scale
    if (tid < 128) {
      int r = tid >> 5, kk = tid & 31;
      x4S[r * 32 + kk] = x[((size_t)(b0 + r) * 100 + t) * 32 + kk];
    }
    if (tid < 4) {
      const float* dp = dt + ((size_t)(b0 + tid) * 100 + t) * 2;
      sclS[tid] = (dp[1] - dp[0]) * (1.f / 24.f);
    }
    __syncthreads();

    // ===== RNN partials: K=288 concat, (jq 64, kc 8), 4 cols x 4 rows
    // acc_r = f4 of 4 cols for row r (col-major f4 -> conflict-free reduce)
    {
      const int jq = tid & 63, kc = tid >> 6;
      float4 acc0 = make_float4(0, 0, 0, 0), acc1 = acc0, acc2 = acc0, acc3 = acc0;
#pragma unroll 3
      for (int gg = 0; gg < 9; ++gg) {
        int g = kc * 9 + gg;                         // k = 4g
        float4 w0 = wcat4[g * 256 + 4 * jq + 0];
        float4 w1 = wcat4[g * 256 + 4 * jq + 1];
        float4 w2 = wcat4[g * 256 + 4 * jq + 2];
        float4 w3 = wcat4[g * 256 + 4 * jq + 3];
        float4 y0 = (g < 8) ? x44[0 * 8 + g] : h44[0 * 64 + (g - 8)];
        float4 y1 = (g < 8) ? x44[1 * 8 + g] : h44[1 * 64 + (g - 8)];
        float4 y2 = (g < 8) ? x44[2 * 8 + g] : h44[2 * 64 + (g - 8)];
        float4 y3 = (g < 8) ? x44[3 * 8 + g] : h44[3 * 64 + (g - 8)];
        acc0.x = fma4(acc0.x, y0, w0); acc0.y = fma4(acc0.y, y0, w1);
        acc0.z = fma4(acc0.z, y0, w2); acc0.w = fma4(acc0.w, y0, w3);
        acc1.x = fma4(acc1.x, y1, w0); acc1.y = fma4(acc1.y, y1, w1);
        acc1.z = fma4(acc1.z, y1, w2); acc1.w = fma4(acc1.w, y1, w3);
        acc2.x = fma4(acc2.x, y2, w0); acc2.y = fma4(acc2.y, y2, w1);
        acc2.z = fma4(acc2.z, y2, w2); acc2.w = fma4(acc2.w, y2, w3);
        acc3.x = fma4(acc3.x, y3, w0); acc3.y = fma4(acc3.y, y3, w1);
        acc3.z = fma4(acc3.z, y3, w2); acc3.w = fma4(acc3.w, y3, w3);
      }
      pr1_4[tid * 5 + 0] = acc0;   // slot tid = kc*64 + jq, slot idx = row
      pr1_4[tid * 5 + 1] = acc1;
      pr1_4[tid * 5 + 2] = acc2;
      pr1_4[tid * 5 + 3] = acc3;
    }
    __syncthreads();
    // ===== RNN reduce: h += tanh(sum partials + bias)
    {
#pragma unroll
      for (int oo = 0; oo < 2; ++oo) {
        int o = tid + oo * 512;
        int r = o >> 8, j = o & 255;          // r wave-uniform
        int q = j >> 2, n = j & 3;            // n stride-1 across lanes
        float s = bcS[j];
#pragma unroll
        for (int kc = 0; kc < 8; ++kc)
          s += prS[(kc * 64 + q) * 20 + r * 4 + n];
        hS[o] += tfast(s);
      }
    }
    __syncthreads();

    // ===== ODE: 4 RK4 steps, hs = 0.25
#pragma unroll 1
    for (int os = 0; os < 4; ++os) {
#pragma unroll
      for (int s = 0; s < 4; ++s) {
        // --- L1 partials: f4 = 4 neurons (4q1..+3), one row per slot
        {
          const float4* ysrc = (s == 0) ? h44 : yc44;
          float4 a0 = make_float4(0, 0, 0, 0), a1 = a0, a2 = a0, a3 = a0;
#pragma unroll
          for (int g = 0; g < 2; ++g) {
            float4 y0 = ysrc[0 * 64 + kc1 * 2 + g];
            float4 y1 = ysrc[1 * 64 + kc1 * 2 + g];
            float4 y2 = ysrc[2 * 64 + kc1 * 2 + g];
            float4 y3 = ysrc[3 * 64 + kc1 * 2 + g];
            a0.x = fma4(a0.x, y0, w1r[0][g]); a0.y = fma4(a0.y, y0, w1r[1][g]);
            a0.z = fma4(a0.z, y0, w1r[2][g]); a0.w = fma4(a0.w, y0, w1r[3][g]);
            a1.x = fma4(a1.x, y1, w1r[0][g]); a1.y = fma4(a1.y, y1, w1r[1][g]);
            a1.z = fma4(a1.z, y1, w1r[2][g]); a1.w = fma4(a1.w, y1, w1r[3][g]);
            a2.x = fma4(a2.x, y2, w1r[0][g]); a2.y = fma4(a2.y, y2, w1r[1][g]);
            a2.z = fma4(a2.z, y2, w1r[2][g]); a2.w = fma4(a2.w, y2, w1r[3][g]);
            a3.x = fma4(a3.x, y3, w1r[0][g]); a3.y = fma4(a3.y, y3, w1r[1][g]);
            a3.z = fma4(a3.z, y3, w1r[2][g]); a3.w = fma4(a3.w, y3, w1r[3][g]);
          }
          pr1_4[tid * 5 + 0] = a0;   // slot tid = kc1*16 + q1
          pr1_4[tid * 5 + 1] = a1;
          pr1_4[tid * 5 + 2] = a2;
          pr1_4[tid * 5 + 3] = a3;
        }
        __syncthreads();
        // --- L1 reduce + tanh -> mdS[r][64]
        if (tid < 256) {
          int r = tid >> 6, j = tid & 63;     // r wave-uniform
          int q = j >> 2, n = j & 3;          // n stride-1
          float sv = ob1S[j];
#pragma unroll
          for (int kc = 0; kc < 32; ++kc)
            sv += prS[(kc * 16 + q) * 20 + r * 4 + n];
          mdS[r * 64 + j] = tfast(sv);
        }
        __syncthreads();
        // --- L2 partials: f4 = 4 cols (4cq2..+3), one row per slot
        {
          float4 b0v = make_float4(0, 0, 0, 0), b1v = b0v, b2v = b0v, b3v = b0v;
#pragma unroll
          for (int g = 0; g < 2; ++g) {
            float4 m0 = md4[0 * 16 + kc2 * 2 + g];
            float4 m1 = md4[1 * 16 + kc2 * 2 + g];
            float4 m2 = md4[2 * 16 + kc2 * 2 + g];
            float4 m3 = md4[3 * 16 + kc2 * 2 + g];
            b0v.x = fma4(b0v.x, m0, w2r[0][g]); b0v.y = fma4(b0v.y, m0, w2r[1][g]);
            b0v.z = fma4(b0v.z, m0, w2r[2][g]); b0v.w = fma4(b0v.w, m0, w2r[3][g]);
            b1v.x = fma4(b1v.x, m1, w2r[0][g]); b1v.y = fma4(b1v.y, m1, w2r[1][g]);
            b1v.z = fma4(b1v.z, m1, w2r[2][g]); b1v.w = fma4(b1v.w, m1, w2r[3][g]);
            b2v.x = fma4(b2v.x, m2, w2r[0][g]); b2v.y = fma4(b2v.y, m2, w2r[1][g]);
            b2v.z = fma4(b2v.z, m2, w2r[2][g]); b2v.w = fma4(b2v.w, m2, w2r[3][g]);
            b3v.x = fma4(b3v.x, m3, w2r[0][g]); b3v.y = fma4(b3v.y, m3, w2r[1][g]);
            b3v.z = fma4(b3v.z, m3, w2r[2][g]); b3v.w = fma4(b3v.w, m3, w2r[3][g]);
          }
          pr2_4[tid * 5 + 0] = b0v;  // slot tid = kc2*64 + cq2
          pr2_4[tid * 5 + 1] = b1v;
          pr2_4[tid * 5 + 2] = b2v;
          pr2_4[tid * 5 + 3] = b3v;
        }
        __syncthreads();
        // --- L2 reduce + RK4 state update (2 outputs/thread)
        {
#pragma unroll
          for (int oo = 0; oo < 2; ++oo) {
            int o = tid + oo * 512;
            int r = o >> 8, j = o & 255;      // r wave-uniform
            int q = j >> 2, n = j & 3;        // n stride-1
            float sv = ob2S[j];
#pragma unroll
            for (int kc = 0; kc < 8; ++kc)
              sv += prS2[(kc * 64 + q) * 20 + r * 4 + n];
            float kv = sv * sclS[r];
            if (s == 0)      { acS[o] = kv;        ycS[o] = hS[o] + 0.125f * kv; }
            else if (s == 1) { acS[o] += 2.f * kv; ycS[o] = hS[o] + 0.125f * kv; }
            else if (s == 2) { acS[o] += 2.f * kv; ycS[o] = hS[o] + 0.25f  * kv; }
            else             { hS[o] += (0.25f / 6.f) * (acS[o] + kv); }
          }
        }
        __syncthreads();
      }
    }

    // ===== heads
    // l1 partials: (cq 32, kc 16): 4 cols x 4 rows x 16 k  -> prS
    {
      const int cq = tid & 31, kc = tid >> 5;
      float4 c0 = make_float4(0, 0, 0, 0), c1 = c0, c2 = c0, c3 = c0;
#pragma unroll 2
      for (int g = 0; g < 4; ++g) {
        int kg = kc * 4 + g;
        float4 w0 = l1w4[kg * 128 + 4 * cq + 0];
        float4 w1 = l1w4[kg * 128 + 4 * cq + 1];
        float4 w2 = l1w4[kg * 128 + 4 * cq + 2];
        float4 w3 = l1w4[kg * 128 + 4 * cq + 3];
        float4 y0 = h44[0 * 64 + kg], y1 = h44[1 * 64 + kg];
        float4 y2 = h44[2 * 64 + kg], y3 = h44[3 * 64 + kg];
        c0.x = fma4(c0.x, y0, w0); c0.y = fma4(c0.y, y0, w1);
        c0.z = fma4(c0.z, y0, w2); c0.w = fma4(c0.w, y0, w3);
        c1.x = fma4(c1.x, y1, w0); c1.y = fma4(c1.y, y1, w1);
        c1.z = fma4(c1.z, y1, w2); c1.w = fma4(c1.w, y1, w3);
        c2.x = fma4(c2.x, y2, w0); c2.y = fma4(c2.y, y2, w1);
        c2.z = fma4(c2.z, y2, w2); c2.w = fma4(c2.w, y2, w3);
        c3.x = fma4(c3.x, y3, w0); c3.y = fma4(c3.y, y3, w1);
        c3.z = fma4(c3.z, y3, w2); c3.w = fma4(c3.w, y3, w3);
      }
      pr1_4[tid * 5 + 0] = c0;
      pr1_4[tid * 5 + 1] = c1;
      pr1_4[tid * 5 + 2] = c2;
      pr1_4[tid * 5 + 3] = c3;
    }
    // sig1 partials: (cq 64, kc 8): 4 cols x 4 rows x 32 k  -> prS2
    {
      const int cq = tid & 63, kc = tid >> 6;
      float4 d0 = make_float4(0, 0, 0, 0), d1 = d0, d2 = d0, d3 = d0;
#pragma unroll 2
      for (int g = 0; g < 8; ++g) {
        int kg = kc * 8 + g;
        float4 w0 = sw14[kg * 256 + 4 * cq + 0];
        float4 w1 = sw14[kg * 256 + 4 * cq + 1];
        float4 w2 = sw14[kg * 256 + 4 * cq + 2];
        float4 w3 = sw14[kg * 256 + 4 * cq + 3];
        float4 y0 = h44[0 * 64 + kg], y1 = h44[1 * 64 + kg];
        float4 y2 = h44[2 * 64 + kg], y3 = h44[3 * 64 + kg];
        d0.x = fma4(d0.x, y0, w0); d0.y = fma4(d0.y, y0, w1);
        d0.z = fma4(d0.z, y0, w2); d0.w = fma4(d0.w, y0, w3);
        d1.x = fma4(d1.x, y1, w0); d1.y = fma4(d1.y, y1, w1);
        d1.z = fma4(d1.z, y1, w2); d1.w = fma4(d1.w, y1, w3);
        d2.x = fma4(d2.x, y2, w0); d2.y = fma4(d2.y, y2, w1);
        d2.z = fma4(d2.z, y2, w2); d2.w = fma4(d2.w, y2, w3);
        d3.x = fma4(d3.x, y3, w0); d3.y = fma4(d3.y, y3, w1);
        d3.z = fma4(d3.z, y3, w2); d3.w = fma4(d3.w, y3, w3);
      }
      pr2_4[tid * 5 + 0] = d0;
      pr2_4[tid * 5 + 1] = d1;
      pr2_4[tid * 5 + 2] = d2;
      pr2_4[tid * 5 + 3] = d3;
    }
    __syncthreads();
    // l1 reduce -> relu -> l1oS
    {
      int r = tid >> 7, j2 = tid & 127;       // r wave-uniform
      int q = j2 >> 2, nn = j2 & 3;           // nn stride-1
      float s = l1bS[j2];
#pragma unroll
      for (int kc = 0; kc < 16; ++kc)
        s += prS[(kc * 32 + q) * 20 + r * 4 + nn];
      l1oS[r * 128 + j2] = fmaxf(s, 0.f);
    }
    // sig1 reduce -> tanh -> sgS
    {
#pragma unroll
      for (int oo = 0; oo < 2; ++oo) {
        int o = tid + oo * 512;
        int r = o >> 8, j = o & 255;
        int q = j >> 2, nn = j & 3;
        float s = sb1S[j];
#pragma unroll
        for (int kc = 0; kc < 8; ++kc)
          s += prS2[(kc * 64 + q) * 20 + r * 4 + nn];
        sgS[o] = tfast(s);
      }
    }
    __syncthreads();
    // final dot-products: wave wv: row = wv&3, head = wv>>2
    {
      const int r = wv & 3;
      if (wv < 4) {
        float pm = l1oS[r * 128 + ln] * muwS[ln]
                 + l1oS[r * 128 + 64 + ln] * muwS[64 + ln];
#pragma unroll
        for (int off = 32; off > 0; off >>= 1) pm += __shfl_down(pm, off);
        if (ln == 0) out[(size_t)(b0 + r) * 100 + t] = pm + mub;
      } else {
        float ps = sgS[r * 256 + ln] * sw2S[ln]
                 + sgS[r * 256 + 64 + ln] * sw2S[64 + ln]
                 + sgS[r * 256 + 128 + ln] * sw2S[128 + ln]
                 + sgS[r * 256 + 192 + ln] * sw2S[192 + ln];
#pragma unroll
        for (int off = 32; off > 0; off >>= 1) ps += __shfl_down(ps, off);
        if (ln == 0) {
          float z = ps + sb2;
          float sp = fmaxf(z, 0.f) + log1pf(expf(-fabsf(z)));
          out[(size_t)102400 + (size_t)(b0 + r) * 100 + t] = sp;
        }
      }
    }
    // no barrier needed: next-step staging writes x4S/sclS (disjoint from
    // l1oS/sgS reads above); first write to prS is after the stage barrier.
  }
}

extern "C" void kernel_launch(void* const* d_in, const int* in_sizes, int n_in,
                              void* d_out, int out_size, void* d_ws, size_t ws_size,
                              hipStream_t stream) {
  const float* dt  = (const float*)d_in[0];
  const float* x   = (const float*)d_in[1];
  const float* Wih = (const float*)d_in[2];
  const float* bih = (const float*)d_in[3];
  const float* Whh = (const float*)d_in[4];
  const float* bhh = (const float*)d_in[5];
  const float* ow1 = (const float*)d_in[6];
  const float* ob1 = (const float*)d_in[7];
  const float* ow2 = (const float*)d_in[8];
  const float* ob2 = (const float*)d_in[9];
  const float* l1w = (const float*)d_in[10];
  const float* l1b = (const float*)d_in[11];
  const float* muw = (const float*)d_in[12];
  const float* mub = (const float*)d_in[13];
  const float* sw1 = (const float*)d_in[14];
  const float* sb1 = (const float*)d_in[15];
  const float* sw2 = (const float*)d_in[16];
  const float* sb2 = (const float*)d_in[17];
  float* ws  = (float*)d_ws;
  float* out = (float*)d_out;

  hipFuncSetAttribute((const void*)odernn_main,
                      hipFuncAttributeMaxDynamicSharedMemorySize, SMEM_BYTES);

  prep_transpose<<<WS_TOT / 256, 256, 0, stream>>>(Wih, Whh, l1w, sw1, ws);
  odernn_main<<<256, NT, SMEM_BYTES, stream>>>(dt, x, bih, bhh, ow1, ob1, ow2, ob2,
                                               l1b, muw, mub, sb1, sw2, sb2, ws, out);
}